// Round 12
// baseline (186.563 us; speedup 1.0000x reference)
//
#include <hip/hip_runtime.h>
#include <hip/hip_bf16.h>
#include <stdint.h>

#define B_TOTAL 131072

typedef __attribute__((ext_vector_type(8))) short short8;
typedef __attribute__((ext_vector_type(16))) float float16v;
typedef __attribute__((ext_vector_type(2))) float f32x2;

// ===== fragment-linear ws layout (32x32x16, k-PERMUTED F2/F3) — frozen r9 =====
#define CH_U16 24576
#define oF2 14336
#define oF3 22528
#define BF16_TOT (6 * CH_U16)          // 147456 u16
#define F32_BASE (BF16_TOT / 2)        // 73728 floats
#define sB1 0
#define sB2 768
#define sB3 1152
#define sW4 1344
#define sB4 1536
#define sCP 1542
#define sDC 1578
#define NSMALL 1584
#define CONV_TOT (BF16_TOT + NSMALL)

// LDS: per-chamber buffer = F1 (28 KB, chunks 0..27) + F3 (4 KB, LDS chunks
// 28..31 <- global chunks 44..47) = 16384 u16. TWO chamber buffers resident.
#define bWF3 14336
#define BUFC 16384

#define GLB_AS __attribute__((address_space(1)))
#define LDS_AS __attribute__((address_space(3)))

__device__ __forceinline__ float bf16_as_f32(uint16_t u) {
    union { uint32_t i; float f; } v; v.i = ((uint32_t)u) << 16; return v.f;
}
__device__ __forceinline__ uint16_t f2bf(float f) {
    uint32_t u = __float_as_uint(f);
    return (uint16_t)((u + 0x7FFFu + ((u >> 16) & 1u)) >> 16);   // RNE
}
__device__ __forceinline__ float sigmoidf_fast(float x) {
    return __builtin_amdgcn_rcpf(1.0f + __expf(-x));
}
__device__ __forceinline__ float siluf(float x) { return x * sigmoidf_fast(x); }

__device__ __forceinline__ float readsrc(const void* p, int off, bool bf) {
    return bf ? bf16_as_f32(((const uint16_t*)p)[off]) : ((const float*)p)[off];
}

__device__ __forceinline__ uint32_t cvtpk_bf16(float lo, float hi) {
    uint32_t r;
    asm("v_cvt_pk_bf16_f32 %0, %1, %2" : "=v"(r) : "v"(lo), "v"(hi));
    return r;
}

// r11 silu pair (pure C, shared-rcp; verified PASS, absmax 0.00390625)
__device__ __forceinline__ uint32_t silu2bf(float a, float b) {
    float ea = __expf(-a), eb = __expf(-b);
    f32x2 e; e.x = ea; e.y = eb;
    f32x2 one; one.x = 1.0f; one.y = 1.0f;
    f32x2 d = e + one;
    float p = d.x * d.y;
    float rp = __builtin_amdgcn_rcpf(p);
    f32x2 s; s.x = d.y * rp; s.y = d.x * rp;
    f32x2 x; x.x = a; x.y = b;
    f32x2 o = x * s;
    return cvtpk_bf16(o.x, o.y);
}

// Fragment-linear bf16 weights + f32 smalls. (frozen since round 9)
__global__ void convert_kernel(const void* W1, const void* b1, const void* W2, const void* b2,
                               const void* W3, const void* b3, const void* W4, const void* b4,
                               const void* cp, const void* dc, uint16_t* __restrict__ wsb) {
    const bool bf = (((const uint32_t*)cp)[0] != 0u);
    int idx = blockIdx.x * 256 + threadIdx.x;
    if (idx >= CONV_TOT) return;
    if (idx < BF16_TOT) {
        int c = idx / CH_U16;
        int r = idx - c * CH_U16;
        float v;
        if (r < oF2) {                       // F1: standard k-slots, pad 100->112
            int f = r >> 9, rem = r & 511, l = rem >> 3, e = rem & 7;
            int ct = f / 7, kb = f - ct * 7;
            int n = ct * 32 + (l & 31), k = kb * 16 + (l >> 5) * 8 + e;
            v = (k < 100) ? readsrc(W1, c * 12800 + k * 128 + n, bf) : 0.0f;
        } else if (r < oF3) {                // F2: PERMUTED k-slots
            int j = r - oF2;
            int f = j >> 9, rem = j & 511, l = rem >> 3, e = rem & 7;
            int ct2 = f >> 3, kb = f & 7;
            int n = ct2 * 32 + (l & 31);
            int k = 32 * (kb >> 1) + 8 * (e >> 1) + 4 * (l >> 5) + 2 * (kb & 1) + (e & 1);
            v = readsrc(W2, c * 8192 + k * 64 + n, bf);
        } else {                             // F3: PERMUTED k-slots
            int j = r - oF3;
            int kb = j >> 9, rem = j & 511, l = rem >> 3, e = rem & 7;
            int n = (l & 31);
            int k = 32 * (kb >> 1) + 8 * (e >> 1) + 4 * (l >> 5) + 2 * (kb & 1) + (e & 1);
            v = readsrc(W3, c * 2048 + k * 32 + n, bf);
        }
        wsb[idx] = f2bf(v);
    } else {
        int fi = idx - BF16_TOT;
        float v;
        if      (fi < sB2)  v = readsrc(b1, fi, bf);
        else if (fi < sB3)  v = readsrc(b2, fi - sB2, bf);
        else if (fi < sW4)  v = readsrc(b3, fi - sB3, bf);
        else if (fi < sB4)  v = readsrc(W4, fi - sW4, bf);
        else if (fi < sCP)  v = readsrc(b4, fi - sB4, bf);
        else if (fi < sDC)  v = readsrc(cp, fi - sCP, bf);
        else                v = readsrc(dc, fi - sDC, bf);
        ((float*)wsb)[F32_BASE + fi] = v;
    }
}

union Frag { uint4 u4; uint2 u2[2]; uint32_t u[4]; short8 s8; uint16_t h[8]; };

// Per-chamber pipeline state (SROA'd to registers; all indices static).
struct ChSt {
    float16v acc;
    Frag pk1f[2][4];
    Frag pk2f[2][2];
    const uint16_t* buf;    // LDS F1/F3 base for this chamber
    const uint16_t* gF2;    // global F2 base
    int c;
};

// Tile t: 0..3 = L1 col-tiles, 4..5 = L2 col-tiles, 6 = L3. MF = acc-init +
// MFMA burst (matrix pipe); SL = silu burst (VALU pipe). Independent across
// chambers -> emitted alternately for two chambers to overlap the pipes.
template<int T>
__device__ __forceinline__ void MF(ChSt& st, const float* sB, const Frag* R,
                                   int q2, int l) {
    if constexpr (T < 4) {
#pragma unroll
        for (int ar = 0; ar < 4; ++ar) {           // bias-fold: C-in = b1
            const float4 bv = *(const float4*)(sB + sB1 + st.c * 128 + T * 32 + ar * 8 + q2 * 4);
            st.acc[4 * ar + 0] = bv.x; st.acc[4 * ar + 1] = bv.y;
            st.acc[4 * ar + 2] = bv.z; st.acc[4 * ar + 3] = bv.w;
        }
        const uint16_t* fp1 = st.buf + (T * 7) * 512 + l * 8;
#pragma unroll
        for (int kb = 0; kb < 7; ++kb) {
            Frag Af; Af.u4 = *(const uint4*)(fp1 + kb * 512);
            st.acc = __builtin_amdgcn_mfma_f32_32x32x16_bf16(Af.s8, R[kb].s8, st.acc, 0, 0, 0);
        }
    } else if constexpr (T < 6) {
        const int ct2 = T - 4;
#pragma unroll
        for (int ar = 0; ar < 4; ++ar) {           // bias-fold: C-in = b2
            const float4 bv = *(const float4*)(sB + sB2 + st.c * 64 + ct2 * 32 + ar * 8 + q2 * 4);
            st.acc[4 * ar + 0] = bv.x; st.acc[4 * ar + 1] = bv.y;
            st.acc[4 * ar + 2] = bv.z; st.acc[4 * ar + 3] = bv.w;
        }
#pragma unroll
        for (int kb = 0; kb < 8; ++kb) {
            Frag Af; Af.u4 = *(const uint4*)(st.gF2 + ((ct2 * 8 + kb) * 64 + l) * 8);
            st.acc = __builtin_amdgcn_mfma_f32_32x32x16_bf16(Af.s8, st.pk1f[kb & 1][kb >> 1].s8, st.acc, 0, 0, 0);
        }
    } else {
#pragma unroll
        for (int ar = 0; ar < 4; ++ar) {           // bias-fold: C-in = b3
            const float4 bv = *(const float4*)(sB + sB3 + st.c * 32 + ar * 8 + q2 * 4);
            st.acc[4 * ar + 0] = bv.x; st.acc[4 * ar + 1] = bv.y;
            st.acc[4 * ar + 2] = bv.z; st.acc[4 * ar + 3] = bv.w;
        }
        const uint16_t* fp3 = st.buf + bWF3 + l * 8;
#pragma unroll
        for (int kb = 0; kb < 4; ++kb) {
            Frag Af; Af.u4 = *(const uint4*)(fp3 + kb * 512);
            st.acc = __builtin_amdgcn_mfma_f32_32x32x16_bf16(Af.s8, st.pk2f[kb & 1][kb >> 1].s8, st.acc, 0, 0, 0);
        }
    }
}

template<int T>
__device__ __forceinline__ void SL(ChSt& st, const float* sB, int q2, float& rv) {
    if constexpr (T < 4) {
#pragma unroll
        for (int ar = 0; ar < 4; ++ar) {
            st.pk1f[0][T].u[ar] = silu2bf(st.acc[4 * ar + 0], st.acc[4 * ar + 1]);
            st.pk1f[1][T].u[ar] = silu2bf(st.acc[4 * ar + 2], st.acc[4 * ar + 3]);
        }
    } else if constexpr (T < 6) {
#pragma unroll
        for (int ar = 0; ar < 4; ++ar) {
            st.pk2f[0][T - 4].u[ar] = silu2bf(st.acc[4 * ar + 0], st.acc[4 * ar + 1]);
            st.pk2f[1][T - 4].u[ar] = silu2bf(st.acc[4 * ar + 2], st.acc[4 * ar + 3]);
        }
    } else {
        float part = 0.f;                          // L4 (frozen scalar path)
#pragma unroll
        for (int ar = 0; ar < 4; ++ar) {
            const float4 wv = *(const float4*)(sB + sW4 + st.c * 32 + ar * 8 + q2 * 4);
            part = fmaf(siluf(st.acc[4 * ar + 0]), wv.x, part);
            part = fmaf(siluf(st.acc[4 * ar + 1]), wv.y, part);
            part = fmaf(siluf(st.acc[4 * ar + 2]), wv.z, part);
            part = fmaf(siluf(st.acc[4 * ar + 3]), wv.w, part);
        }
        part += __shfl_xor(part, 32);
        rv = part + sB[sB4 + st.c];
    }
}

// Cross-chamber software pipeline: two independent chambers per wave, skewed
// by half a tile — every silu burst (VALU) is adjacent to an independent MFMA
// tile (matrix pipe) of the other chamber, so in-order wave issue overlaps
// the two pipes. 14 braces/pair + prologue/drain. LDS: pair of F1+F3 buffers
// (64 KB) + consts = 71.9 KB -> 2 blocks/CU; F2 streams from global (L2-hot,
// proven placement-neutral r2/r3). 512 thr = 8 waves x 32 rows, grid 512.
__global__ __launch_bounds__(512, 4)
void chambers_mfma(const void* __restrict__ resv, const uint16_t* __restrict__ wsb,
                   const uint32_t* __restrict__ cpw, float* __restrict__ outF) {
    const float* wsf = (const float*)wsb;
    const bool bfin = (cpw[0] != 0u);
    const int tid = threadIdx.x;
    const int w = tid >> 6, l = tid & 63;
    const int l5 = l & 31, q2 = l >> 5;
    const int row = blockIdx.x * 256 + w * 32 + l5;

    __shared__ __align__(16) uint16_t sW[2 * BUFC];  // 64 KB: chamber pair F1+F3
    __shared__ __align__(16) float sB[NSMALL];       // 6336 B biases/consts

#define STAGE_PAIR(P)                                                          \
    {                                                                          \
        _Pragma("unroll")                                                      \
        for (int sl = 0; sl < 2; ++sl) {                                       \
            const uint16_t* gsrc = wsb + (2 * (P) + sl) * CH_U16;              \
            uint16_t* ldst = sW + sl * BUFC;                                   \
            _Pragma("unroll")                                                  \
            for (int rr = 0; rr < 4; ++rr) {                                   \
                const int i = rr * 8 + w;              /* 0..31, 1 KB */       \
                const int gi = (i < 28) ? i : (i + 16);                        \
                __builtin_amdgcn_global_load_lds(                              \
                    (const GLB_AS uint32_t*)(gsrc + gi * 512 + l * 8),         \
                    (LDS_AS uint32_t*)(ldst + i * 512), 16, 0, 0);             \
            }                                                                  \
        }                                                                      \
    }

    STAGE_PAIR(0)
    for (int i = tid; i < NSMALL; i += 512) sB[i] = wsf[F32_BASE + i];

    // ===== res row fragments (B operand): k = kb*16 + q2*8 + e, K 100->112 =====
    Frag R[7];
    if (bfin) {
        const uint16_t* bp = (const uint16_t*)resv + (size_t)row * 100;
#pragma unroll
        for (int kb = 0; kb < 6; ++kb) {
            const int k0 = kb * 16 + q2 * 8;
            R[kb].u2[0] = *(const uint2*)(bp + k0);
            R[kb].u2[1] = *(const uint2*)(bp + k0 + 4);
        }
        R[6].u4 = make_uint4(0, 0, 0, 0);
        if (q2 == 0) R[6].u2[0] = *(const uint2*)(bp + 96);
    } else {
        const float* fp = (const float*)resv + (size_t)row * 100;
#pragma unroll
        for (int kb = 0; kb < 6; ++kb) {
            const int k0 = kb * 16 + q2 * 8;
            float4 x0 = *(const float4*)(fp + k0);
            float4 x1 = *(const float4*)(fp + k0 + 4);
            R[kb].u[0] = cvtpk_bf16(x0.x, x0.y);
            R[kb].u[1] = cvtpk_bf16(x0.z, x0.w);
            R[kb].u[2] = cvtpk_bf16(x1.x, x1.y);
            R[kb].u[3] = cvtpk_bf16(x1.z, x1.w);
        }
        R[6].u4 = make_uint4(0, 0, 0, 0);
        if (q2 == 0) {
            float4 x0 = *(const float4*)(fp + 96);
            R[6].u[0] = cvtpk_bf16(x0.x, x0.y);
            R[6].u[1] = cvtpk_bf16(x0.z, x0.w);
        }
    }

    __syncthreads();               // pair 0 + sB visible

    float raw0 = 0.f, raw1 = 0.f, raw2 = 0.f, raw3 = 0.f, raw4 = 0.f, raw5 = 0.f;
    ChSt A, B;

#pragma unroll 1
    for (int p = 0; p < 3; ++p) {
        const int cA = 2 * p, cB = 2 * p + 1;
        A.c = cA; A.buf = sW;        A.gF2 = wsb + cA * CH_U16 + oF2;
        B.c = cB; B.buf = sW + BUFC; B.gF2 = wsb + cB * CH_U16 + oF2;
        float rvA = 0.f, rvB = 0.f;

        MF<0>(A, sB, R, q2, l);
        MF<0>(B, sB, R, q2, l);  SL<0>(A, sB, q2, rvA);
        MF<1>(A, sB, R, q2, l);  SL<0>(B, sB, q2, rvB);
        MF<1>(B, sB, R, q2, l);  SL<1>(A, sB, q2, rvA);
        MF<2>(A, sB, R, q2, l);  SL<1>(B, sB, q2, rvB);
        MF<2>(B, sB, R, q2, l);  SL<2>(A, sB, q2, rvA);
        MF<3>(A, sB, R, q2, l);  SL<2>(B, sB, q2, rvB);
        MF<3>(B, sB, R, q2, l);  SL<3>(A, sB, q2, rvA);
        MF<4>(A, sB, R, q2, l);  SL<3>(B, sB, q2, rvB);
        MF<4>(B, sB, R, q2, l);  SL<4>(A, sB, q2, rvA);
        MF<5>(A, sB, R, q2, l);  SL<4>(B, sB, q2, rvB);
        MF<5>(B, sB, R, q2, l);  SL<5>(A, sB, q2, rvA);
        MF<6>(A, sB, R, q2, l);  SL<5>(B, sB, q2, rvB);
        MF<6>(B, sB, R, q2, l);  SL<6>(A, sB, q2, rvA);
        SL<6>(B, sB, q2, rvB);

        raw0 = (cA == 0) ? rvA : raw0;
        raw2 = (cA == 2) ? rvA : raw2;
        raw4 = (cA == 4) ? rvA : raw4;
        raw1 = (cB == 1) ? rvB : raw1;
        raw3 = (cB == 3) ? rvB : raw3;
        raw5 = (cB == 5) ? rvB : raw5;

        if (p < 2) {
            __syncthreads();           // all waves done reading this pair's sW
            STAGE_PAIR(p + 1)
            __syncthreads();           // next pair staged
        }
    }

    // ===== Coupling fixed point (redundant over q2; frozen) =====
    const float rv6[6] = {raw0, raw1, raw2, raw3, raw4, raw5};
    float av[6];
#pragma unroll
    for (int c = 0; c < 6; ++c) av[c] = sigmoidf_fast(rv6[c]);
    const float K = 0.02f;
#pragma unroll 1
    for (int it = 0; it < 5; ++it) {
        float tt[6];
#pragma unroll
        for (int i = 0; i < 6; ++i) tt[i] = av[i] * sB[sDC + i] * K;
#pragma unroll
        for (int j = 0; j < 6; ++j) {
            float dl = 0.0f;
#pragma unroll
            for (int i = 0; i < 6; ++i) dl = fmaf(tt[i], sB[sCP + i * 6 + j], dl);
            av[j] = sigmoidf_fast(rv6[j] + dl);
        }
    }
    if (q2 == 0) {
        float2* oa = (float2*)(outF + (size_t)row * 6);
        oa[0] = make_float2(av[0], av[1]);
        oa[1] = make_float2(av[2], av[3]);
        oa[2] = make_float2(av[4], av[5]);
        float2* orw = (float2*)(outF + (size_t)B_TOTAL * 6 + (size_t)row * 6);
        orw[0] = make_float2(rv6[0], rv6[1]);
        orw[1] = make_float2(rv6[2], rv6[3]);
        orw[2] = make_float2(rv6[4], rv6[5]);
    }
#undef STAGE_PAIR
}

extern "C" void kernel_launch(void* const* d_in, const int* in_sizes, int n_in,
                              void* d_out, int out_size, void* d_ws, size_t ws_size,
                              hipStream_t stream) {
    uint16_t* wsb = (uint16_t*)d_ws;
    convert_kernel<<<(CONV_TOT + 255) / 256, 256, 0, stream>>>(
        d_in[1], d_in[2], d_in[3], d_in[4], d_in[5], d_in[6], d_in[7], d_in[8],
        d_in[9], d_in[10], wsb);
    chambers_mfma<<<B_TOTAL / 256, 512, 0, stream>>>(
        d_in[0], wsb, (const uint32_t*)d_in[9], (float*)d_out);
}